// Round 2
// baseline (440.194 us; speedup 1.0000x reference)
//
#include <hip/hip_runtime.h>
#include <hip/hip_bf16.h>

// ---------- bf16 helpers (bf16 arrays handled as ushort) ----------
__device__ __forceinline__ float bf2f(unsigned int u16) {
    return __uint_as_float(u16 << 16);
}
__device__ __forceinline__ unsigned short f2bf(float f) {
    unsigned int u = __float_as_uint(f);
    unsigned int lsb = (u >> 16) & 1u;
    u += 0x7fffu + lsb;
    return (unsigned short)(u >> 16);
}

// ---------------- kernel 0: runtime encoding detection ----------------
// flags[0] = 1 if float inputs are bf16-packed, 0 if fp32
// flags[1] = 1 if edge_index is int64 (little-endian), 0 if int32
__global__ __launch_bounds__(256) void k_detect(const unsigned int* __restrict__ xw,
                                                const unsigned int* __restrict__ eiw,
                                                int* __restrict__ flags) {
    __shared__ int votes[2];
    int tid = threadIdx.x;
    if (tid == 0) { votes[0] = 0; votes[1] = 0; }
    __syncthreads();
    // float-dtype vote: if x is bf16-packed, the LOW 16 bits of each 32-bit
    // word are a bf16 value of N(0,1) data -> exponent bits in ~[113,130].
    // If x is fp32, low 16 bits are mantissa tail -> uniform random.
    unsigned int w = xw[tid];
    unsigned int lo = w & 0xffffu;
    unsigned int elo = (lo >> 7) & 0xffu;
    int bfvote = (lo == 0u || (elo >= 100u && elo <= 140u)) ? 1 : 0;
    // int64 vote: odd 32-bit words of an int64 array of values < 2^31 are 0.
    int nzvote = (eiw[2 * tid + 1] != 0u) ? 1 : 0;
    atomicAdd(&votes[0], bfvote);
    atomicAdd(&votes[1], nzvote);
    __syncthreads();
    if (tid == 0) {
        flags[0] = (votes[0] >= 160) ? 1 : 0;
        flags[1] = (votes[1] == 0) ? 1 : 0;
    }
}

// ---------------- kernel 1: in-degree over dst ----------------
__global__ __launch_bounds__(256) void k_deg(const int* __restrict__ ei,
                                             const int* __restrict__ flags,
                                             int* __restrict__ deg, int E, int Nn) {
    int e = blockIdx.x * 256 + threadIdx.x;
    if (e >= E) return;
    int is64 = flags[1];
    int d = is64 ? ei[2 * (E + e)] : ei[E + e];
    if ((unsigned)d >= (unsigned)Nn) return;  // defensive
    atomicAdd(&deg[d], 1);
}

// ---------------- kernel 2: h = x @ W1 (fp32 accum) ----------------
// block = 256 threads, 256 nodes/block; thread = (nodeq 0..63, hq 0..3)
__global__ __launch_bounds__(256) void k_gemm1(const void* __restrict__ xraw,
                                               const void* __restrict__ w1raw,
                                               const int* __restrict__ flags,
                                               float* __restrict__ h, int Nn) {
    __shared__ float sWt[16 * 132];  // W1^T [hid][k], padded rows
    const int isbf = flags[0];
    const ushort* xb = (const ushort*)xraw;
    const float* xf = (const float*)xraw;
    int tid = threadIdx.x;
    if (isbf) {
        const ushort* w1 = (const ushort*)w1raw;
        for (int i = tid; i < 2048; i += 256) {
            int k = i >> 4, j = i & 15;
            sWt[j * 132 + k] = bf2f(w1[i]);
        }
    } else {
        const float* w1 = (const float*)w1raw;
        for (int i = tid; i < 2048; i += 256) {
            int k = i >> 4, j = i & 15;
            sWt[j * 132 + k] = w1[i];
        }
    }
    __syncthreads();
    int hq = tid & 3;
    int nodeq = tid >> 2;
    int n0 = blockIdx.x * 256 + nodeq * 4;
    float acc[4][4] = {};
    for (int ko = 0; ko < 16; ++ko) {
        float xv[4][8];
        #pragma unroll
        for (int r = 0; r < 4; ++r) {
            int n = n0 + r;
            if (n < Nn) {
                if (isbf) {
                    uint4 q = *reinterpret_cast<const uint4*>(xb + (size_t)n * 128 + ko * 8);
                    xv[r][0] = bf2f(q.x & 0xffffu); xv[r][1] = bf2f(q.x >> 16);
                    xv[r][2] = bf2f(q.y & 0xffffu); xv[r][3] = bf2f(q.y >> 16);
                    xv[r][4] = bf2f(q.z & 0xffffu); xv[r][5] = bf2f(q.z >> 16);
                    xv[r][6] = bf2f(q.w & 0xffffu); xv[r][7] = bf2f(q.w >> 16);
                } else {
                    const float4* p = reinterpret_cast<const float4*>(xf + (size_t)n * 128 + ko * 8);
                    float4 a = p[0], b = p[1];
                    xv[r][0] = a.x; xv[r][1] = a.y; xv[r][2] = a.z; xv[r][3] = a.w;
                    xv[r][4] = b.x; xv[r][5] = b.y; xv[r][6] = b.z; xv[r][7] = b.w;
                }
            } else {
                #pragma unroll
                for (int u = 0; u < 8; ++u) xv[r][u] = 0.f;
            }
        }
        #pragma unroll
        for (int c = 0; c < 4; ++c) {
            const float* wr = &sWt[(hq * 4 + c) * 132 + ko * 8];
            float4 w0 = *reinterpret_cast<const float4*>(wr);
            float4 w1v = *reinterpret_cast<const float4*>(wr + 4);
            #pragma unroll
            for (int r = 0; r < 4; ++r) {
                acc[r][c] += xv[r][0] * w0.x + xv[r][1] * w0.y + xv[r][2] * w0.z + xv[r][3] * w0.w
                           + xv[r][4] * w1v.x + xv[r][5] * w1v.y + xv[r][6] * w1v.z + xv[r][7] * w1v.w;
            }
        }
    }
    #pragma unroll
    for (int r = 0; r < 4; ++r) {
        int n = n0 + r;
        if (n < Nn) {
            float4 o = make_float4(acc[r][0], acc[r][1], acc[r][2], acc[r][3]);
            *reinterpret_cast<float4*>(h + (size_t)n * 16 + hq * 4) = o;
        }
    }
}

// ---------------- kernel 3: dinv + self-loop init of agg ----------------
__global__ __launch_bounds__(256) void k_init(const int* __restrict__ deg,
                                              const float* __restrict__ h,
                                              float* __restrict__ dinv,
                                              float* __restrict__ agg, int Nn) {
    int t = blockIdx.x * 256 + threadIdx.x;
    int n = t >> 4, j = t & 15;
    if (n >= Nn) return;
    float dv = rsqrtf((float)(deg[n] + 1));  // +1 self loop
    if (j == 0) dinv[n] = dv;
    agg[n * 16 + j] = h[n * 16 + j] * (dv * dv);
}

// ---------------- kernel 4: edge scatter-add ----------------
__global__ __launch_bounds__(256) void k_edge(const int* __restrict__ ei,
                                              const int* __restrict__ flags,
                                              const float* __restrict__ dinv,
                                              const float* __restrict__ h,
                                              float* __restrict__ agg, int E, int Nn) {
    int t = blockIdx.x * 256 + threadIdx.x;
    int e = t >> 4, j = t & 15;
    if (e >= E) return;
    int is64 = flags[1];
    int s, d;
    if (is64) { s = ei[2 * e]; d = ei[2 * (E + e)]; }
    else      { s = ei[e];     d = ei[E + e]; }
    if ((unsigned)s >= (unsigned)Nn || (unsigned)d >= (unsigned)Nn) return;  // defensive
    float w = dinv[s] * dinv[d];
    atomicAdd(&agg[d * 16 + j], h[s * 16 + j] * w);
}

// ---------------- kernel 5: bias+relu -> @Wp+bp -> softmax -> out ----------------
__global__ __launch_bounds__(256) void k_final(const float* __restrict__ agg,
                                               const void* __restrict__ b1raw,
                                               const void* __restrict__ wpraw,
                                               const void* __restrict__ bpraw,
                                               const int* __restrict__ flags,
                                               void* __restrict__ outraw, int Nn) {
    __shared__ float sWp[256];
    __shared__ float sA[256];
    const int isbf = flags[0];
    int tid = threadIdx.x;
    if (isbf) sWp[tid] = bf2f(((const ushort*)wpraw)[tid]);
    else      sWp[tid] = ((const float*)wpraw)[tid];
    int n0 = blockIdx.x * 16;
    int nl = tid >> 4, c = tid & 15;
    int n = n0 + nl;
    float b1v = isbf ? bf2f(((const ushort*)b1raw)[c]) : ((const float*)b1raw)[c];
    float bpv = isbf ? bf2f(((const ushort*)bpraw)[c]) : ((const float*)bpraw)[c];
    float av = (n < Nn) ? agg[(size_t)n * 16 + c] : 0.f;
    sA[tid] = fmaxf(av + b1v, 0.f);
    __syncthreads();
    float acc = bpv;
    #pragma unroll
    for (int j = 0; j < 16; ++j) acc += sA[nl * 16 + j] * sWp[j * 16 + c];
    float m = acc;
    #pragma unroll
    for (int off = 1; off < 16; off <<= 1) m = fmaxf(m, __shfl_xor(m, off, 16));
    float ev = __expf(acc - m);
    float s = ev;
    #pragma unroll
    for (int off = 1; off < 16; off <<= 1) s += __shfl_xor(s, off, 16);
    if (n < Nn) {
        float v = ev / s;
        if (isbf) ((ushort*)outraw)[(size_t)n * 16 + c] = f2bf(v);
        else      ((float*)outraw)[(size_t)n * 16 + c] = v;
    }
}

extern "C" void kernel_launch(void* const* d_in, const int* in_sizes, int n_in,
                              void* d_out, int out_size, void* d_ws, size_t ws_size,
                              hipStream_t stream) {
    const void* x  = d_in[0];             // [N,128] bf16 or fp32
    const void* W1 = d_in[1];             // [128,16]
    const void* b1 = d_in[2];             // [16]
    const void* Wp = d_in[3];             // [16,16]
    const void* bp = d_in[4];             // [16]
    const int*  ei = (const int*)d_in[5]; // [2,E] int32 or int64

    int Nn = in_sizes[0] / 128;
    int E  = in_sizes[5] / 2;

    char* ws = (char*)d_ws;
    int*   flags = (int*)ws;                                    // 64 B
    float* h     = (float*)(ws + 64);                           // N*16 f32
    float* agg   = (float*)(ws + 64 + (size_t)Nn * 16 * 4);     // N*16 f32
    float* dinv  = (float*)(ws + 64 + (size_t)Nn * 32 * 4);     // N f32
    int*   deg   = (int*)  (ws + 64 + (size_t)Nn * 33 * 4);     // N i32

    hipMemsetAsync(deg, 0, (size_t)Nn * 4, stream);
    k_detect<<<1, 256, 0, stream>>>((const unsigned int*)x, (const unsigned int*)ei, flags);
    k_deg<<<(E + 255) / 256, 256, 0, stream>>>(ei, flags, deg, E, Nn);
    k_gemm1<<<(Nn + 255) / 256, 256, 0, stream>>>(x, W1, flags, h, Nn);
    k_init<<<(Nn * 16 + 255) / 256, 256, 0, stream>>>(deg, h, dinv, agg, Nn);
    int edge_blocks = (int)(((size_t)E * 16 + 255) / 256);
    k_edge<<<edge_blocks, 256, 0, stream>>>(ei, flags, dinv, h, agg, E, Nn);
    k_final<<<(Nn + 15) / 16, 256, 0, stream>>>(agg, b1, Wp, bp, flags, d_out, Nn);
}